// Round 1
// baseline (429.668 us; speedup 1.0000x reference)
//
#include <hip/hip_runtime.h>
#include <hip/hip_bf16.h>
#include <math.h>

#define NN 10000
#define EE 160000
#define DIM 256
#define EPS_BN 1e-5f

// ---------------- degree histogram ----------------
__global__ void k_deg(const int* __restrict__ dst, int* __restrict__ deg_cnt, int E_) {
    int e = blockIdx.x * 256 + threadIdx.x;
    if (e < E_) atomicAdd(&deg_cnt[dst[e]], 1);
}

// ---------------- exclusive scan over deg (1 block) ----------------
__global__ __launch_bounds__(256) void k_scan(const int* __restrict__ deg_cnt,
                                              int* __restrict__ row_ofs,
                                              int* __restrict__ cursor,
                                              float* __restrict__ inv_deg) {
    __shared__ int part[256];
    int t = threadIdx.x;
    const int CH = (NN + 255) / 256; // 40
    int base = t * CH;
    int s = 0;
    for (int i = 0; i < CH; ++i) {
        int idx = base + i;
        if (idx < NN) s += deg_cnt[idx];
    }
    part[t] = s;
    __syncthreads();
    if (t == 0) {
        int run = 0;
        for (int i = 0; i < 256; ++i) { int v = part[i]; part[i] = run; run += v; }
        row_ofs[NN] = run;
    }
    __syncthreads();
    int off = part[t];
    for (int i = 0; i < CH; ++i) {
        int idx = base + i;
        if (idx < NN) {
            row_ofs[idx] = off;
            cursor[idx]  = off;
            int d = deg_cnt[idx];
            inv_deg[idx] = 1.0f / (float)(d > 1 ? d : 1);
            off += d;
        }
    }
}

// ---------------- CSR fill ----------------
__global__ void k_fill(const int* __restrict__ src, const int* __restrict__ dst,
                       int* __restrict__ cursor, int* __restrict__ csr_src, int E_) {
    int e = blockIdx.x * 256 + threadIdx.x;
    if (e < E_) {
        int p = atomicAdd(&cursor[dst[e]], 1);
        csr_src[p] = src[e];
    }
}

// ---------------- mean aggregation (CSR gather, no atomics) ----------------
__global__ __launch_bounds__(256) void k_agg(const float* __restrict__ H,
                                             const int* __restrict__ row_ofs,
                                             const int* __restrict__ csr_src,
                                             const float* __restrict__ inv_deg,
                                             float* __restrict__ mean) {
    int n = blockIdx.x;
    int f = threadIdx.x;
    int s = row_ofs[n], e = row_ofs[n + 1];
    float acc = 0.f;
    int j = s;
    for (; j + 4 <= e; j += 4) {
        int i0 = csr_src[j], i1 = csr_src[j + 1], i2 = csr_src[j + 2], i3 = csr_src[j + 3];
        float a = H[i0 * DIM + f];
        float b = H[i1 * DIM + f];
        float c = H[i2 * DIM + f];
        float d = H[i3 * DIM + f];
        acc += (a + b) + (c + d);
    }
    for (; j < e; ++j) acc += H[csr_src[j] * DIM + f];
    mean[n * DIM + f] = acc * inv_deg[n];
}

// ---------------- GEMM: Z = H@Ws + MEAN@Wn + bias ----------------
// 64x64 tile, 256 threads, 4x4 micro-tile, K = 256 per phase, 2 phases.
#define BM 64
#define BN 64
#define BK 16
__global__ __launch_bounds__(256) void k_gemm(const float* __restrict__ A0,
                                              const float* __restrict__ A1,
                                              const float* __restrict__ B0,
                                              const float* __restrict__ B1,
                                              const float* __restrict__ bias,
                                              float* __restrict__ Z, int nrows) {
    __shared__ float As[BK][BM + 4];
    __shared__ float Bs[BK][BN + 4];
    int bx = blockIdx.x % (DIM / BN);
    int by = blockIdx.x / (DIM / BN);
    int row0 = by * BM, col0 = bx * BN;
    int t = threadIdx.x;
    int tx = t % 16, ty = t / 16;
    // A-load mapping: each thread loads float4 of A: m = t>>2 (0..63), k4 = (t&3)*4
    int am = t >> 2, ak = (t & 3) * 4;
    // B-load mapping: k = t>>4 (0..15), n4 = (t&15)*4
    int bk = t >> 4, bn = (t & 15) * 4;
    float acc[4][4] = {};
    for (int phase = 0; phase < 2; ++phase) {
        const float* A = phase ? A1 : A0;
        const float* B = phase ? B1 : B0;
        for (int k0 = 0; k0 < DIM; k0 += BK) {
            int ar = row0 + am;
            float4 av = make_float4(0.f, 0.f, 0.f, 0.f);
            if (ar < nrows) av = *(const float4*)(A + ar * DIM + k0 + ak);
            As[ak + 0][am] = av.x;
            As[ak + 1][am] = av.y;
            As[ak + 2][am] = av.z;
            As[ak + 3][am] = av.w;
            float4 bv = *(const float4*)(B + (k0 + bk) * DIM + col0 + bn);
            *(float4*)&Bs[bk][bn] = bv;
            __syncthreads();
#pragma unroll
            for (int k = 0; k < BK; ++k) {
                float4 a4 = *(float4*)&As[k][ty * 4];
                float4 b4 = *(float4*)&Bs[k][tx * 4];
                float a[4] = {a4.x, a4.y, a4.z, a4.w};
                float b[4] = {b4.x, b4.y, b4.z, b4.w};
#pragma unroll
                for (int i = 0; i < 4; ++i)
#pragma unroll
                    for (int j = 0; j < 4; ++j) acc[i][j] += a[i] * b[j];
            }
            __syncthreads();
        }
    }
#pragma unroll
    for (int i = 0; i < 4; ++i) {
        int r = row0 + ty * 4 + i;
        if (r < nrows) {
            int c = col0 + tx * 4;
            float4 o;
            o.x = acc[i][0] + bias[c + 0];
            o.y = acc[i][1] + bias[c + 1];
            o.z = acc[i][2] + bias[c + 2];
            o.w = acc[i][3] + bias[c + 3];
            *(float4*)(Z + r * DIM + c) = o;
        }
    }
}

// ---------------- per-column sum / sumsq partials ----------------
__global__ __launch_bounds__(256) void k_stats(const float* __restrict__ Z,
                                               float* __restrict__ stats, int nrows) {
    int c = threadIdx.x;
    int r0 = blockIdx.x * 32;
    float s = 0.f, s2 = 0.f;
    for (int i = 0; i < 32; ++i) {
        int r = r0 + i;
        if (r < nrows) {
            float v = Z[r * DIM + c];
            s += v;
            s2 += v * v;
        }
    }
    atomicAdd(&stats[c], s);
    atomicAdd(&stats[DIM + c], s2);
}

// ---------------- BN normalize + activation ----------------
__global__ __launch_bounds__(256) void k_norm(const float* __restrict__ Z,
                                              const float* __restrict__ stats,
                                              const float* __restrict__ g,
                                              const float* __restrict__ be,
                                              float* __restrict__ out, int nrows, int act) {
    int c = threadIdx.x;
    float mu = stats[c] * (1.0f / NN);
    float var = stats[DIM + c] * (1.0f / NN) - mu * mu;
    float sc = rsqrtf(var + EPS_BN) * g[c];
    float sh = be[c] - mu * sc;
    int r0 = blockIdx.x * 32;
    for (int i = 0; i < 32; ++i) {
        int r = r0 + i;
        if (r >= nrows) break;
        float v = Z[r * DIM + c] * sc + sh;
        if (act) v = 1.0f / (1.0f + expf(-v));
        else v = fmaxf(v, 0.0f);
        out[r * DIM + c] = v;
    }
}

extern "C" void kernel_launch(void* const* d_in, const int* in_sizes, int n_in,
                              void* d_out, int out_size, void* d_ws, size_t ws_size,
                              hipStream_t stream) {
    const float* x   = (const float*)d_in[0];
    const int*   src = (const int*)d_in[1];
    const int*   dst = (const int*)d_in[2];
    const float* Ws[3] = {(const float*)d_in[3], (const float*)d_in[8],  (const float*)d_in[13]};
    const float* Wn[3] = {(const float*)d_in[4], (const float*)d_in[9],  (const float*)d_in[14]};
    const float* bb[3] = {(const float*)d_in[5], (const float*)d_in[10], (const float*)d_in[15]};
    const float* gg[3] = {(const float*)d_in[6], (const float*)d_in[11], (const float*)d_in[16]};
    const float* be[3] = {(const float*)d_in[7], (const float*)d_in[12], (const float*)d_in[17]};
    float* out = (float*)d_out;

    // ---- workspace layout (bytes) ----
    char* ws = (char*)d_ws;
    size_t off = 0;
    const size_t MAT = (size_t)NN * DIM * sizeof(float); // 10,240,000
    float* mean  = (float*)(ws + off); off += MAT;
    float* zbuf  = (float*)(ws + off); off += MAT;
    float* hbuf  = (float*)(ws + off); off += MAT;
    float* stats = (float*)(ws + off); off += 3 * 2 * DIM * sizeof(float);
    float* inv_deg = (float*)(ws + off); off += ((NN * 4 + 255) / 256) * 256;
    int* deg_cnt = (int*)(ws + off); off += ((NN * 4 + 255) / 256) * 256;
    int* row_ofs = (int*)(ws + off); off += (((NN + 1) * 4 + 255) / 256) * 256;
    int* cursor  = (int*)(ws + off); off += ((NN * 4 + 255) / 256) * 256;
    int* csr_src = (int*)(ws + off); off += (size_t)EE * 4;
    (void)ws_size;

    // ---- zero what must be zero ----
    hipMemsetAsync(deg_cnt, 0, NN * sizeof(int), stream);
    hipMemsetAsync(stats, 0, 3 * 2 * DIM * sizeof(float), stream);

    // ---- CSR build (layer-invariant) ----
    k_deg<<<(EE + 255) / 256, 256, 0, stream>>>(dst, deg_cnt, EE);
    k_scan<<<1, 256, 0, stream>>>(deg_cnt, row_ofs, cursor, inv_deg);
    k_fill<<<(EE + 255) / 256, 256, 0, stream>>>(src, dst, cursor, csr_src, EE);

    const int gemm_grid = ((NN + BM - 1) / BM) * (DIM / BN); // 157*4
    const int rows_grid = (NN + 31) / 32;                    // 313

    for (int L = 0; L < 3; ++L) {
        const float* hin = (L == 0) ? x : hbuf;
        float* hout = (L == 2) ? out : hbuf;
        int act = (L == 2) ? 1 : 0;
        k_agg<<<NN, 256, 0, stream>>>(hin, row_ofs, csr_src, inv_deg, mean);
        k_gemm<<<gemm_grid, 256, 0, stream>>>(hin, mean, Ws[L], Wn[L], bb[L], zbuf, NN);
        k_stats<<<rows_grid, 256, 0, stream>>>(zbuf, stats + L * 2 * DIM, NN);
        k_norm<<<rows_grid, 256, 0, stream>>>(zbuf, stats + L * 2 * DIM, gg[L], be[L],
                                              hout, NN, act);
    }
}

// Round 2
// 312.800 us; speedup vs baseline: 1.3736x; 1.3736x over previous
//
#include <hip/hip_runtime.h>
#include <hip/hip_bf16.h>
#include <math.h>

#define NN 10000
#define EE 160000
#define DIM 256
#define KK 512            // concatenated K = 2*DIM
#define EPS_BN 1e-5f

typedef __attribute__((ext_vector_type(8)))  short bf16x8;
typedef __attribute__((ext_vector_type(16))) float f32x16;

static __device__ __forceinline__ unsigned short f2bf(float f) {
    unsigned u = __float_as_uint(f);
    unsigned r = (u + 0x7fffu + ((u >> 16) & 1u)) >> 16;   // RTNE
    return (unsigned short)r;
}
static __device__ __forceinline__ float bflo(unsigned v) { return __uint_as_float(v << 16); }
static __device__ __forceinline__ float bfhi(unsigned v) { return __uint_as_float(v & 0xffff0000u); }
static __device__ __forceinline__ unsigned packbf(float a, float b) {
    return (unsigned)f2bf(a) | ((unsigned)f2bf(b) << 16);
}

// ---------------- degree histogram ----------------
__global__ void k_deg(const int* __restrict__ dst, int* __restrict__ deg_cnt, int E_) {
    int e = blockIdx.x * 256 + threadIdx.x;
    if (e < E_) atomicAdd(&deg_cnt[dst[e]], 1);
}

// ---------------- exclusive scan over deg (1 block) ----------------
__global__ __launch_bounds__(256) void k_scan(const int* __restrict__ deg_cnt,
                                              int* __restrict__ row_ofs,
                                              int* __restrict__ cursor,
                                              float* __restrict__ inv_deg) {
    __shared__ int part[256];
    int t = threadIdx.x;
    const int CH = (NN + 255) / 256; // 40
    int base = t * CH;
    int s = 0;
    for (int i = 0; i < CH; ++i) {
        int idx = base + i;
        if (idx < NN) s += deg_cnt[idx];
    }
    part[t] = s;
    __syncthreads();
    if (t == 0) {
        int run = 0;
        for (int i = 0; i < 256; ++i) { int v = part[i]; part[i] = run; run += v; }
        row_ofs[NN] = run;
    }
    __syncthreads();
    int off = part[t];
    for (int i = 0; i < CH; ++i) {
        int idx = base + i;
        if (idx < NN) {
            row_ofs[idx] = off;
            cursor[idx]  = off;
            int d = deg_cnt[idx];
            inv_deg[idx] = 1.0f / (float)(d > 1 ? d : 1);
            off += d;
        }
    }
}

// ---------------- CSR fill ----------------
__global__ void k_fill(const int* __restrict__ src, const int* __restrict__ dst,
                       int* __restrict__ cursor, int* __restrict__ csr_src, int E_) {
    int e = blockIdx.x * 256 + threadIdx.x;
    if (e < E_) {
        int p = atomicAdd(&cursor[dst[e]], 1);
        csr_src[p] = src[e];
    }
}

// ---------------- x (fp32) -> hcat left half (bf16) ----------------
__global__ __launch_bounds__(256) void k_cvt_x(const float* __restrict__ x,
                                               unsigned short* __restrict__ hcat) {
    int g = blockIdx.x * 256 + threadIdx.x;   // 640000 threads: row = g>>6, 4 cols each
    int r = g >> 6;
    int c4 = (g & 63) * 4;
    float4 v = *(const float4*)(x + (size_t)r * DIM + c4);
    uint2 p;
    p.x = packbf(v.x, v.y);
    p.y = packbf(v.z, v.w);
    *(uint2*)(hcat + (size_t)r * KK + c4) = p;
}

// ---------------- [Ws;Wn] -> WcatT bf16 [n=256][k=512] ----------------
__global__ __launch_bounds__(256) void k_cvt_w(const float* __restrict__ Ws,
                                               const float* __restrict__ Wn,
                                               unsigned short* __restrict__ wcatT) {
    int g = blockIdx.x * 256 + threadIdx.x;   // 131072 threads: k = g>>8, n = g&255
    int k = g >> 8;
    int n = g & 255;
    float v = (k < DIM) ? Ws[(size_t)k * DIM + n] : Wn[(size_t)(k - DIM) * DIM + n];
    wcatT[(size_t)n * KK + k] = f2bf(v);
}

// ---------------- mean aggregation: wave-per-node bf16 gather ----------------
__global__ __launch_bounds__(256) void k_agg(const unsigned short* __restrict__ hcat,
                                             const int* __restrict__ row_ofs,
                                             const int* __restrict__ csr_src,
                                             const float* __restrict__ inv_deg) {
    int wave = threadIdx.x >> 6;
    int lane = threadIdx.x & 63;
    int node = blockIdx.x * 4 + wave;         // grid = 2500 -> exactly 10000
    int s = row_ofs[node], e = row_ofs[node + 1];
    const uint2* base = (const uint2*)hcat;   // 128 uint2 per row (KK shorts)
    float a0 = 0.f, a1 = 0.f, a2 = 0.f, a3 = 0.f;
    int j = s;
    for (; j + 2 <= e; j += 2) {
        int i0 = csr_src[j], i1 = csr_src[j + 1];
        uint2 v0 = base[(size_t)i0 * 128 + lane];
        uint2 v1 = base[(size_t)i1 * 128 + lane];
        a0 += bflo(v0.x) + bflo(v1.x);
        a1 += bfhi(v0.x) + bfhi(v1.x);
        a2 += bflo(v0.y) + bflo(v1.y);
        a3 += bfhi(v0.y) + bfhi(v1.y);
    }
    if (j < e) {
        uint2 v0 = base[(size_t)csr_src[j] * 128 + lane];
        a0 += bflo(v0.x); a1 += bfhi(v0.x); a2 += bflo(v0.y); a3 += bfhi(v0.y);
    }
    float inv = inv_deg[node];
    uint2 p;
    p.x = packbf(a0 * inv, a1 * inv);
    p.y = packbf(a2 * inv, a3 * inv);
    ((uint2*)hcat)[(size_t)node * 128 + 64 + lane] = p;
}

// ---------------- MFMA GEMM: Z = hcat @ Wcat, + column stats ----------------
// block = 256 thr = 4 waves, block tile 128x64, wave tile 32x64 (two 32x32 MFMAs)
// no LDS: A/B fragments streamed from global (B is 256KB, L2-resident)
__global__ __launch_bounds__(256) void k_gemm(const unsigned short* __restrict__ hcat,
                                              const unsigned short* __restrict__ wcatT,
                                              float* __restrict__ Z,
                                              float* __restrict__ stats) {
    int t = threadIdx.x;
    int wave = t >> 6, lane = t & 63;
    int m = lane & 31, half = lane >> 5;
    int mblk = blockIdx.x >> 2;               // 0..78
    int nblk = blockIdx.x & 3;
    int row0 = mblk * 128 + wave * 32;
    int col0 = nblk * 64;

    int ar = row0 + m; if (ar > NN - 1) ar = NN - 1;   // clamp; invalid C rows masked later
    const unsigned short* Ap  = hcat  + (size_t)ar * KK + half * 8;
    const unsigned short* Bp0 = wcatT + (size_t)(col0 + m) * KK + half * 8;
    const unsigned short* Bp1 = Bp0 + (size_t)32 * KK;

    f32x16 acc0, acc1;
#pragma unroll
    for (int i = 0; i < 16; ++i) { acc0[i] = 0.f; acc1[i] = 0.f; }

#pragma unroll 8
    for (int k0 = 0; k0 < KK; k0 += 16) {
        bf16x8 a  = *(const bf16x8*)(Ap  + k0);
        bf16x8 b0 = *(const bf16x8*)(Bp0 + k0);
        bf16x8 b1 = *(const bf16x8*)(Bp1 + k0);
        acc0 = __builtin_amdgcn_mfma_f32_32x32x16_bf16(a, b0, acc0, 0, 0, 0);
        acc1 = __builtin_amdgcn_mfma_f32_32x32x16_bf16(a, b1, acc1, 0, 0, 0);
    }

#pragma unroll
    for (int ct = 0; ct < 2; ++ct) {
        int cc = col0 + ct * 32 + m;
        float s = 0.f, s2 = 0.f;
#pragma unroll
        for (int reg = 0; reg < 16; ++reg) {
            int r = row0 + (reg & 3) + 8 * (reg >> 2) + 4 * half;
            if (r < NN) {
                float v = (ct == 0) ? acc0[reg] : acc1[reg];
                Z[(size_t)r * DIM + cc] = v;
                s += v;
                s2 += v * v;
            }
        }
        s  += __shfl_down(s, 32);
        s2 += __shfl_down(s2, 32);
        if (half == 0) {
            atomicAdd(&stats[cc], s);
            atomicAdd(&stats[DIM + cc], s2);
        }
    }
}

// ---------------- BN normalize + activation ----------------
// act=0: relu -> write bf16 into hcat left half; act=1: sigmoid -> fp32 out
__global__ __launch_bounds__(256) void k_norm(const float* __restrict__ Z,
                                              const float* __restrict__ stats,
                                              const float* __restrict__ g,
                                              const float* __restrict__ be,
                                              unsigned short* __restrict__ hcat,
                                              float* __restrict__ out, int act) {
    int t = threadIdx.x;
    int c4 = (t & 63) * 4;
    int ri = t >> 6;
    int rowbase = blockIdx.x * 8;             // grid 1250 -> exactly 10000 rows
    float sc[4], sh[4];
#pragma unroll
    for (int i = 0; i < 4; ++i) {
        int c = c4 + i;
        float mu  = stats[c] * (1.0f / NN);
        float var = stats[DIM + c] * (1.0f / NN) - mu * mu;
        float k = rsqrtf(var + EPS_BN) * g[c];
        sc[i] = k;
        sh[i] = be[c] - mu * k;
    }
#pragma unroll
    for (int it = 0; it < 2; ++it) {
        int r = rowbase + ri + it * 4;
        float4 v = *(const float4*)(Z + (size_t)r * DIM + c4);
        v.x = v.x * sc[0] + sh[0];
        v.y = v.y * sc[1] + sh[1];
        v.z = v.z * sc[2] + sh[2];
        v.w = v.w * sc[3] + sh[3];
        if (act) {
            v.x = 1.0f / (1.0f + __expf(-v.x));
            v.y = 1.0f / (1.0f + __expf(-v.y));
            v.z = 1.0f / (1.0f + __expf(-v.z));
            v.w = 1.0f / (1.0f + __expf(-v.w));
            *(float4*)(out + (size_t)r * DIM + c4) = v;
        } else {
            v.x = fmaxf(v.x, 0.f); v.y = fmaxf(v.y, 0.f);
            v.z = fmaxf(v.z, 0.f); v.w = fmaxf(v.w, 0.f);
            uint2 p;
            p.x = packbf(v.x, v.y);
            p.y = packbf(v.z, v.w);
            *(uint2*)(hcat + (size_t)r * KK + c4) = p;
        }
    }
}

extern "C" void kernel_launch(void* const* d_in, const int* in_sizes, int n_in,
                              void* d_out, int out_size, void* d_ws, size_t ws_size,
                              hipStream_t stream) {
    const float* x   = (const float*)d_in[0];
    const int*   src = (const int*)d_in[1];
    const int*   dst = (const int*)d_in[2];
    const float* Ws[3] = {(const float*)d_in[3], (const float*)d_in[8],  (const float*)d_in[13]};
    const float* Wn[3] = {(const float*)d_in[4], (const float*)d_in[9],  (const float*)d_in[14]};
    const float* gg[3] = {(const float*)d_in[6], (const float*)d_in[11], (const float*)d_in[16]};
    const float* be[3] = {(const float*)d_in[7], (const float*)d_in[12], (const float*)d_in[17]};
    float* out = (float*)d_out;

    // ---- workspace layout ----
    char* ws = (char*)d_ws;
    size_t off = 0;
    unsigned short* hcat = (unsigned short*)(ws + off); off += (size_t)NN * KK * 2;        // 10.24 MB
    float* zbuf = (float*)(ws + off); off += (size_t)NN * DIM * 4;                          // 10.24 MB
    unsigned short* wcatT[3];
    for (int L = 0; L < 3; ++L) { wcatT[L] = (unsigned short*)(ws + off); off += (size_t)DIM * KK * 2; }
    float* stats = (float*)(ws + off); off += 3 * 2 * DIM * sizeof(float);
    float* inv_deg = (float*)(ws + off); off += (size_t)NN * 4;
    int* deg_cnt = (int*)(ws + off); off += (size_t)NN * 4;
    int* row_ofs = (int*)(ws + off); off += (size_t)(NN + 1) * 4; off = (off + 255) & ~(size_t)255;
    int* cursor  = (int*)(ws + off); off += (size_t)NN * 4;
    int* csr_src = (int*)(ws + off); off += (size_t)EE * 4;
    (void)ws_size;

    hipMemsetAsync(deg_cnt, 0, NN * sizeof(int), stream);
    hipMemsetAsync(stats, 0, 3 * 2 * DIM * sizeof(float), stream);

    // ---- converts ----
    k_cvt_x<<<(NN * 64) / 256, 256, 0, stream>>>(x, hcat);
    for (int L = 0; L < 3; ++L)
        k_cvt_w<<<(DIM * KK) / 256, 256, 0, stream>>>(Ws[L], Wn[L], wcatT[L]);

    // ---- CSR build (layer-invariant) ----
    k_deg<<<(EE + 255) / 256, 256, 0, stream>>>(dst, deg_cnt, EE);
    k_scan<<<1, 256, 0, stream>>>(deg_cnt, row_ofs, cursor, inv_deg);
    k_fill<<<(EE + 255) / 256, 256, 0, stream>>>(src, dst, cursor, csr_src, EE);

    const int gemm_grid = ((NN + 127) / 128) * 4;   // 79*4 = 316
    for (int L = 0; L < 3; ++L) {
        k_agg<<<NN / 4, 256, 0, stream>>>(hcat, row_ofs, csr_src, inv_deg);
        k_gemm<<<gemm_grid, 256, 0, stream>>>(hcat, wcatT[L], zbuf, stats + L * 2 * DIM);
        k_norm<<<NN / 8, 256, 0, stream>>>(zbuf, stats + L * 2 * DIM, gg[L], be[L],
                                           hcat, out, (L == 2) ? 1 : 0);
    }
}